// Round 9
// baseline (457.984 us; speedup 1.0000x reference)
//
#include <hip/hip_runtime.h>
#include <hip/hip_cooperative_groups.h>

namespace cg = cooperative_groups;

#define DEV_INLINE __device__ __forceinline__
#define MAXDEG 64  // deg ~ Poisson(12); P(deg>=64) ~ 1e-25 — guarded anyway

// sh[0..8]: l=0,1,2 real spherical harmonics as in reference _sh (first 9 comps)
static DEV_INLINE void sh_l012(float xx, float yy, float zz, float sh[9]) {
    const float s3  = 1.7320508075688772f;
    const float s5  = 2.23606797749979f;
    const float s15 = 3.872983346207417f;
    float r2 = xx * xx + yy * yy + zz * zz;
    sh[0] = 1.0f;
    sh[1] = s3 * xx;
    sh[2] = s3 * yy;
    sh[3] = s3 * zz;
    sh[4] = s15 * xx * yy;
    sh[5] = s15 * yy * zz;
    sh[6] = 0.5f * s5 * (3.0f * zz * zz - r2);
    sh[7] = s15 * xx * zz;
    sh[8] = 0.5f * s15 * (xx * xx - yy * yy);
}

// One cooperative kernel, 4 phases separated by grid.sync():
//  0: zero deg/atoms/out
//  1: prep  — node1[v]=(px,py,pz,b0), node2[v]=(b1,b2), atoms hist;
//             edges: rank=deg[dst]++ (returning atomic), rec[dst*64+rank]={src,ea}
//  2: passA — per dst node (16 lanes), Pkg[v]={P*isd (9), px,py,pz}
//  3: passB — per dst node (16 lanes), LDS mol aggregation -> out
__global__ void __launch_bounds__(256, 4)
k_all(const float* __restrict__ x, const float* __restrict__ pos,
      const float* __restrict__ W1_0, const float* __restrict__ W1_1,
      const float* __restrict__ W1_2, const float* __restrict__ W2_0,
      const float* __restrict__ W2_1, const float* __restrict__ W2_2,
      const int* __restrict__ esrc, const int* __restrict__ edst,
      const float* __restrict__ eattr, const int* __restrict__ batch,
      float4* __restrict__ node1, float2* __restrict__ node2,
      int* __restrict__ deg, int2* __restrict__ rec, int* __restrict__ atoms,
      float4* __restrict__ Pkg, float* __restrict__ out,
      int n_nodes, int n_edges, int n_mol) {
    cg::grid_group grid = cg::this_grid();
    __shared__ float ws[90];
    __shared__ int hist[512];
    __shared__ float smol[512];
    int t = threadIdx.x;
    int g = blockIdx.x * blockDim.x + t;
    int nthreads = gridDim.x * blockDim.x;

    // ---- phase 0: zero workspace counters and output ----
    for (int i = g; i < n_nodes; i += nthreads) deg[i] = 0;
    if (g < n_mol) { atoms[g] = 0; out[g] = 0.f; }
    grid.sync();

    // ---- phase 1: prep ----
    bool nodeBlock = (blockIdx.x * blockDim.x) < n_nodes;  // uniform per block
    if (nodeBlock) {
        const float inv_s30 = 0.18257418583505536f;
        if (t < 30) {
            float s = 0.f;
            for (int u = 0; u < 64; u++) s += W1_0[t * 64 + u] * W2_0[u];
            ws[t] = s * inv_s30;
        } else if (t < 60) {
            int k = t - 30;
            float s = 0.f;
            for (int u = 0; u < 24; u++) s += W1_1[k * 24 + u] * W2_1[u];
            ws[t] = s * inv_s30;
        } else if (t < 90) {
            int k = t - 60;
            float s = 0.f;
            for (int u = 0; u < 16; u++) s += W1_2[k * 16 + u] * W2_2[u];
            ws[t] = s * inv_s30;
        }
        hist[t] = 0;
        hist[t + 256] = 0;
        __syncthreads();
        if (g < n_nodes) {
            const float* xv = x + (size_t)g * 30;
            float s0 = 0.f, s1 = 0.f, s2 = 0.f;
#pragma unroll
            for (int k = 0; k < 30; k++) {
                float xk = xv[k];
                s0 += xk * ws[k];
                s1 += xk * ws[30 + k];
                s2 += xk * ws[60 + k];
            }
            node1[g] = make_float4(pos[g * 3 + 0], pos[g * 3 + 1], pos[g * 3 + 2], s0);
            node2[g] = make_float2(s1, s2);
        }
        // atoms-per-mol histogram (batch sorted => small span per 256-node block)
        int v0 = blockIdx.x * 256;
        int molFirst = batch[min(v0, n_nodes - 1)];
        if (g < n_nodes) atomicAdd(&hist[batch[g] - molFirst], 1);
        __syncthreads();
        int vend = min(v0 + 255, n_nodes - 1);
        int molLast = batch[vend];
        for (int m = t; m <= molLast - molFirst; m += 256)
            if (hist[m] > 0) atomicAdd(atoms + molFirst + m, hist[m]);
    }
    {
        int e = 4 * g;
        if (e + 3 < n_edges) {
            int4 d4 = ((const int4*)edst)[g];
            int4 s4 = ((const int4*)esrc)[g];
            float ea0 = eattr[(size_t)(e + 0) * 10];
            float ea1 = eattr[(size_t)(e + 1) * 10];
            float ea2 = eattr[(size_t)(e + 2) * 10];
            float ea3 = eattr[(size_t)(e + 3) * 10];
            int r0 = atomicAdd(deg + d4.x, 1);
            int r1 = atomicAdd(deg + d4.y, 1);
            int r2 = atomicAdd(deg + d4.z, 1);
            int r3 = atomicAdd(deg + d4.w, 1);
            if (r0 < MAXDEG) rec[d4.x * MAXDEG + r0] = make_int2(s4.x, __float_as_int(ea0));
            if (r1 < MAXDEG) rec[d4.y * MAXDEG + r1] = make_int2(s4.y, __float_as_int(ea1));
            if (r2 < MAXDEG) rec[d4.z * MAXDEG + r2] = make_int2(s4.z, __float_as_int(ea2));
            if (r3 < MAXDEG) rec[d4.w * MAXDEG + r3] = make_int2(s4.w, __float_as_int(ea3));
        } else {
            for (int ee = e; ee < n_edges; ee++) {
                int dst = edst[ee];
                int r = atomicAdd(deg + dst, 1);
                if (r < MAXDEG)
                    rec[dst * MAXDEG + r] =
                        make_int2(esrc[ee], __float_as_int(eattr[(size_t)ee * 10]));
            }
        }
    }
    grid.sync();

    // ---- phase 2: passA (grid-stride over 16-node chunks) ----
    int nchunk = (16 * n_nodes + 255) / 256;  // 3125
    for (int c = blockIdx.x; c < nchunk; c += gridDim.x) {
        int gg = c * 256 + t;
        int v = gg >> 4, r = gg & 15;
        if (v < n_nodes) {
            int d = min(deg[v], MAXDEG);
            const int2* row = rec + (size_t)v * MAXDEG;
            float4 pv = node1[v];
            float acc[9];
#pragma unroll
            for (int m = 0; m < 9; m++) acc[m] = 0.f;
            for (int i = r; i < d; i += 16) {
                int2 rcd = row[i];
                int src = rcd.x;
                float ea = __int_as_float(rcd.y);
                float4 n1 = node1[src];
                float2 n2 = node2[src];
                float dx = n1.x - pv.x, dy = n1.y - pv.y, dz = n1.z - pv.z;
                float sh[9];
                sh_l012(dx, dy, dz, sh);
                acc[0] += ea * n1.w;  // sh[0]==1, b0 in n1.w
#pragma unroll
                for (int m = 1; m < 4; m++) acc[m] += ea * sh[m] * n2.x;
#pragma unroll
                for (int m = 4; m < 9; m++) acc[m] += ea * sh[m] * n2.y;
            }
#pragma unroll
            for (int off = 1; off < 16; off <<= 1)
#pragma unroll
                for (int m = 0; m < 9; m++) acc[m] += __shfl_xor(acc[m], off);
            if (r == 0) {
                float s = (d > 0) ? rsqrtf((float)d) : 0.f;
                float4* o = Pkg + (size_t)v * 3;
                o[0] = make_float4(acc[0] * s, acc[1] * s, acc[2] * s, acc[3] * s);
                o[1] = make_float4(acc[4] * s, acc[5] * s, acc[6] * s, acc[7] * s);
                o[2] = make_float4(acc[8] * s, pv.x, pv.y, pv.z);
            }
        }
    }
    grid.sync();

    // ---- phase 3: passB (grid-stride over 16-node chunks, LDS mol aggregation) ----
    const float i3 = 0.5773502691896258f;     // 1/sqrt(3)
    const float i5 = 0.4472135954999579f;     // 1/sqrt(5)
    const float i104 = 0.09805806756909202f;  // 1/sqrt(104)
    for (int c = blockIdx.x; c < nchunk; c += gridDim.x) {
        smol[t] = 0.f;
        smol[t + 256] = 0.f;
        __syncthreads();
        int gg = c * 256 + t;
        int v = gg >> 4, r = gg & 15;
        int v0 = c * 16;
        int molFirst = batch[min(v0, n_nodes - 1)];
        if (v < n_nodes) {
            int d = min(deg[v], MAXDEG);
            const int2* row = rec + (size_t)v * MAXDEG;
            float4 pv = node1[v];
            float s = 0.f;
            for (int i = r; i < d; i += 16) {
                int2 rcd = row[i];
                int src = rcd.x;
                float ea = __int_as_float(rcd.y);
                const float4* Ps = Pkg + (size_t)src * 3;
                float4 p03 = Ps[0];
                float4 p47 = Ps[1];
                float4 p8p = Ps[2];
                float dx = p8p.y - pv.x, dy = p8p.z - pv.y, dz = p8p.w - pv.z;
                float sh[9];
                sh_l012(dx, dy, dz, sh);
                float t1 = sh[1] * p03.y + sh[2] * p03.z + sh[3] * p03.w;
                float t2 = sh[4] * p47.x + sh[5] * p47.y + sh[6] * p47.z +
                           sh[7] * p47.w + sh[8] * p8p.x;
                s += ea * (p03.x + t1 * i3 + t2 * i5);
            }
#pragma unroll
            for (int off = 1; off < 16; off <<= 1) s += __shfl_xor(s, off);
            if (r == 0) {
                float isd = (d > 0) ? rsqrtf((float)d) : 0.f;
                atomicAdd(&smol[batch[v] - molFirst], s * i104 * isd);
            }
        }
        __syncthreads();
        if (v0 < n_nodes) {
            int vend = min(v0 + 15, n_nodes - 1);
            int nm = batch[vend] - molFirst + 1;
            for (int m = t; m < nm; m += 256) {
                float val = smol[m];
                if (val != 0.f) {
                    int a = atoms[molFirst + m];
                    float inv = (a > 0) ? rsqrtf((float)a) : 0.f;
                    atomicAdd(out + molFirst + m, val * inv);
                }
            }
        }
        __syncthreads();  // smol reused next chunk
    }
}

extern "C" void kernel_launch(void* const* d_in, const int* in_sizes, int n_in,
                              void* d_out, int out_size, void* d_ws, size_t ws_size,
                              hipStream_t stream) {
    const float* pos   = (const float*)d_in[0];
    const float* x     = (const float*)d_in[1];
    const float* eattr = (const float*)d_in[2];
    const float* W1_0  = (const float*)d_in[3];
    const float* W1_1  = (const float*)d_in[4];
    const float* W1_2  = (const float*)d_in[5];
    const float* W2_0  = (const float*)d_in[6];
    const float* W2_1  = (const float*)d_in[7];
    const float* W2_2  = (const float*)d_in[8];
    const int* esrc  = (const int*)d_in[9];
    const int* edst  = (const int*)d_in[10];
    const int* batch = (const int*)d_in[11];

    int n_edges = in_sizes[9];       // 600000
    int n_nodes = in_sizes[11];      // 50000
    int n_mol   = out_size;          // 512
    float* out = (float*)d_out;

    // Workspace layout (nothing needs host-side zeroing; phase 0 zeroes in-kernel).
    char* ws = (char*)d_ws;
    size_t off = 0;
    auto carve = [&](size_t bytes) {
        size_t o = off;
        off = (off + bytes + 255) & ~(size_t)255;
        return o;
    };
    size_t off_deg   = carve((size_t)n_nodes * sizeof(int));
    size_t off_atoms = carve((size_t)n_mol * sizeof(int));
    size_t off_n1    = carve((size_t)n_nodes * sizeof(float4));
    size_t off_n2    = carve((size_t)n_nodes * sizeof(float2));
    size_t off_Pkg   = carve((size_t)n_nodes * 3 * sizeof(float4));
    size_t off_rec   = carve((size_t)n_nodes * MAXDEG * sizeof(int2));  // 25.6 MB
    (void)ws_size;

    int*    deg   = (int*)(ws + off_deg);
    int*    atoms = (int*)(ws + off_atoms);
    float4* node1 = (float4*)(ws + off_n1);
    float2* node2 = (float2*)(ws + off_n2);
    float4* Pkg   = (float4*)(ws + off_Pkg);
    int2*   rec   = (int2*)(ws + off_rec);

    // 1024 blocks x 256 threads = 4 blocks/CU on 256 CUs — co-resident per
    // __launch_bounds__(256,4); cooperative launch validates this.
    void* args[] = {
        (void*)&x, (void*)&pos,
        (void*)&W1_0, (void*)&W1_1, (void*)&W1_2,
        (void*)&W2_0, (void*)&W2_1, (void*)&W2_2,
        (void*)&esrc, (void*)&edst, (void*)&eattr, (void*)&batch,
        (void*)&node1, (void*)&node2, (void*)&deg, (void*)&rec, (void*)&atoms,
        (void*)&Pkg, (void*)&out,
        (void*)&n_nodes, (void*)&n_edges, (void*)&n_mol,
    };
    hipLaunchCooperativeKernel((const void*)k_all, dim3(1024), dim3(256),
                               args, 0, stream);
}

// Round 10
// 149.411 us; speedup vs baseline: 3.0653x; 3.0653x over previous
//
#include <hip/hip_runtime.h>

#define DEV_INLINE __device__ __forceinline__
#define MAXDEG 48  // deg ~ Poisson(12); P(deg>=48) ~ 5.6e-14 — guarded anyway

// sh[0..8]: l=0,1,2 real spherical harmonics as in reference _sh (first 9 comps)
static DEV_INLINE void sh_l012(float xx, float yy, float zz, float sh[9]) {
    const float s3  = 1.7320508075688772f;
    const float s5  = 2.23606797749979f;
    const float s15 = 3.872983346207417f;
    float r2 = xx * xx + yy * yy + zz * zz;
    sh[0] = 1.0f;
    sh[1] = s3 * xx;
    sh[2] = s3 * yy;
    sh[3] = s3 * zz;
    sh[4] = s15 * xx * yy;
    sh[5] = s15 * yy * zz;
    sh[6] = 0.5f * s5 * (3.0f * zz * zz - r2);
    sh[7] = s15 * xx * zz;
    sh[8] = 0.5f * s15 * (xx * xx - yy * yy);
}

// One staging pass:
//  nodes : node1[v]=(px,py,pz,b0), node2[v]=(b1,b2), atoms-per-mol LDS histogram
//  edges : rank = deg[dst]++ (returning atomic), rec[dst*MAXDEG+rank] = {src, ea}
// edst/esrc/eattr are each read exactly once, here.
__global__ void k_prep(const float* __restrict__ x,
                       const float* __restrict__ pos,
                       const float* __restrict__ W1_0, const float* __restrict__ W1_1,
                       const float* __restrict__ W1_2, const float* __restrict__ W2_0,
                       const float* __restrict__ W2_1, const float* __restrict__ W2_2,
                       const int* __restrict__ esrc, const int* __restrict__ edst,
                       const float* __restrict__ eattr, const int* __restrict__ batch,
                       float4* __restrict__ node1, float2* __restrict__ node2,
                       int* __restrict__ deg, int2* __restrict__ rec,
                       int* __restrict__ atoms,
                       int n_nodes, int n_edges) {
    __shared__ float ws[90];
    __shared__ int hist[512];
    int t = threadIdx.x;
    int g = blockIdx.x * blockDim.x + t;
    bool nodeBlock = (blockIdx.x * blockDim.x) < n_nodes;  // uniform per block
    if (nodeBlock) {
        const float inv_s30 = 0.18257418583505536f;
        if (t < 30) {
            float s = 0.f;
            for (int u = 0; u < 64; u++) s += W1_0[t * 64 + u] * W2_0[u];
            ws[t] = s * inv_s30;
        } else if (t < 60) {
            int k = t - 30;
            float s = 0.f;
            for (int u = 0; u < 24; u++) s += W1_1[k * 24 + u] * W2_1[u];
            ws[t] = s * inv_s30;
        } else if (t < 90) {
            int k = t - 60;
            float s = 0.f;
            for (int u = 0; u < 16; u++) s += W1_2[k * 16 + u] * W2_2[u];
            ws[t] = s * inv_s30;
        }
        hist[t] = 0;
        hist[t + 256] = 0;
        __syncthreads();
        if (g < n_nodes) {
            const float* xv = x + (size_t)g * 30;
            float s0 = 0.f, s1 = 0.f, s2 = 0.f;
#pragma unroll
            for (int k = 0; k < 30; k++) {
                float xk = xv[k];
                s0 += xk * ws[k];
                s1 += xk * ws[30 + k];
                s2 += xk * ws[60 + k];
            }
            node1[g] = make_float4(pos[g * 3 + 0], pos[g * 3 + 1], pos[g * 3 + 2], s0);
            node2[g] = make_float2(s1, s2);
        }
        // atoms-per-mol histogram (batch sorted => small span per 256-node block)
        int v0 = blockIdx.x * 256;
        int molFirst = batch[min(v0, n_nodes - 1)];
        if (g < n_nodes) atomicAdd(&hist[batch[g] - molFirst], 1);
        __syncthreads();
        int vend = min(v0 + 255, n_nodes - 1);
        int molLast = batch[vend];
        for (int m = t; m <= molLast - molFirst; m += 256)
            if (hist[m] > 0) atomicAdd(atoms + molFirst + m, hist[m]);
    }
    int e = 4 * g;
    if (e + 3 < n_edges) {
        int4 d4 = ((const int4*)edst)[g];
        int4 s4 = ((const int4*)esrc)[g];
        float ea0 = eattr[(size_t)(e + 0) * 10];
        float ea1 = eattr[(size_t)(e + 1) * 10];
        float ea2 = eattr[(size_t)(e + 2) * 10];
        float ea3 = eattr[(size_t)(e + 3) * 10];
        int r0 = atomicAdd(deg + d4.x, 1);
        int r1 = atomicAdd(deg + d4.y, 1);
        int r2 = atomicAdd(deg + d4.z, 1);
        int r3 = atomicAdd(deg + d4.w, 1);
        if (r0 < MAXDEG) rec[d4.x * MAXDEG + r0] = make_int2(s4.x, __float_as_int(ea0));
        if (r1 < MAXDEG) rec[d4.y * MAXDEG + r1] = make_int2(s4.y, __float_as_int(ea1));
        if (r2 < MAXDEG) rec[d4.z * MAXDEG + r2] = make_int2(s4.z, __float_as_int(ea2));
        if (r3 < MAXDEG) rec[d4.w * MAXDEG + r3] = make_int2(s4.w, __float_as_int(ea3));
    } else {
        for (int ee = e; ee < n_edges; ee++) {
            int dst = edst[ee];
            int r = atomicAdd(deg + dst, 1);
            if (r < MAXDEG)
                rec[dst * MAXDEG + r] = make_int2(esrc[ee], __float_as_int(eattr[(size_t)ee * 10]));
        }
    }
}

// Pass A: 16 lanes per dst node; row at rec + v*MAXDEG.
// Pkg[v] = { P0..P3, P4..P7, P8, px, py, pz } (3 float4; P scaled by isd).
// Also zeroes out[] (first n_mol threads) so passB can atomicAdd into it.
__global__ void k_passA(const float4* __restrict__ node1, const float2* __restrict__ node2,
                        const int2* __restrict__ rec, const int* __restrict__ deg,
                        float4* __restrict__ Pkg, float* __restrict__ out,
                        int n_nodes, int n_mol) {
    int g = blockIdx.x * blockDim.x + threadIdx.x;
    if (g < n_mol) out[g] = 0.f;
    int v = g >> 4, r = g & 15;
    if (v >= n_nodes) return;
    int d = min(deg[v], MAXDEG);
    const int2* row = rec + (size_t)v * MAXDEG;
    float4 pv = node1[v];
    float acc[9];
#pragma unroll
    for (int m = 0; m < 9; m++) acc[m] = 0.f;
    for (int i = r; i < d; i += 16) {
        int2 rcd = row[i];
        int src = rcd.x;
        float ea = __int_as_float(rcd.y);
        float4 n1 = node1[src];
        float2 n2 = node2[src];
        float dx = n1.x - pv.x, dy = n1.y - pv.y, dz = n1.z - pv.z;
        float sh[9];
        sh_l012(dx, dy, dz, sh);
        acc[0] += ea * n1.w;  // sh[0]==1, b0 in n1.w
#pragma unroll
        for (int m = 1; m < 4; m++) acc[m] += ea * sh[m] * n2.x;
#pragma unroll
        for (int m = 4; m < 9; m++) acc[m] += ea * sh[m] * n2.y;
    }
#pragma unroll
    for (int off = 1; off < 16; off <<= 1)
#pragma unroll
        for (int m = 0; m < 9; m++) acc[m] += __shfl_xor(acc[m], off);
    if (r == 0) {
        float s = (d > 0) ? rsqrtf((float)d) : 0.f;
        float4* o = Pkg + (size_t)v * 3;
        o[0] = make_float4(acc[0] * s, acc[1] * s, acc[2] * s, acc[3] * s);
        o[1] = make_float4(acc[4] * s, acc[5] * s, acc[6] * s, acc[7] * s);
        o[2] = make_float4(acc[8] * s, pv.x, pv.y, pv.z);
    }
}

// Pass B: 16 lanes per dst node; LDS mol aggregation; flush val*rsqrt(atoms) directly to out.
__global__ void k_passB(const float4* __restrict__ node1, const float4* __restrict__ Pkg,
                        const int2* __restrict__ rec, const int* __restrict__ deg,
                        const int* __restrict__ batch, const int* __restrict__ atoms,
                        float* __restrict__ out, int n_nodes) {
    __shared__ float smol[512];
    int t = threadIdx.x;
    smol[t] = 0.f;
    smol[t + 256] = 0.f;
    __syncthreads();
    int g = blockIdx.x * blockDim.x + t;
    int v = g >> 4, r = g & 15;
    int v0 = blockIdx.x * 16;                 // 16 nodes per block
    const float i3 = 0.5773502691896258f;     // 1/sqrt(3)
    const float i5 = 0.4472135954999579f;     // 1/sqrt(5)
    const float i104 = 0.09805806756909202f;  // 1/sqrt(104)
    int molFirst = batch[min(v0, n_nodes - 1)];
    if (v < n_nodes) {
        int d = min(deg[v], MAXDEG);
        const int2* row = rec + (size_t)v * MAXDEG;
        float4 pv = node1[v];
        float s = 0.f;
        for (int i = r; i < d; i += 16) {
            int2 rcd = row[i];
            int src = rcd.x;
            float ea = __int_as_float(rcd.y);
            const float4* Ps = Pkg + (size_t)src * 3;
            float4 p03 = Ps[0];
            float4 p47 = Ps[1];
            float4 p8p = Ps[2];
            float dx = p8p.y - pv.x, dy = p8p.z - pv.y, dz = p8p.w - pv.z;
            float sh[9];
            sh_l012(dx, dy, dz, sh);
            float t1 = sh[1] * p03.y + sh[2] * p03.z + sh[3] * p03.w;
            float t2 = sh[4] * p47.x + sh[5] * p47.y + sh[6] * p47.z + sh[7] * p47.w + sh[8] * p8p.x;
            s += ea * (p03.x + t1 * i3 + t2 * i5);
        }
#pragma unroll
        for (int off = 1; off < 16; off <<= 1) s += __shfl_xor(s, off);
        if (r == 0) {
            float isd = (d > 0) ? rsqrtf((float)d) : 0.f;
            atomicAdd(&smol[batch[v] - molFirst], s * i104 * isd);
        }
    }
    __syncthreads();
    if (v0 < n_nodes) {
        int vend = min(v0 + 15, n_nodes - 1);
        int nm = batch[vend] - molFirst + 1;
        for (int m = t; m < nm; m += 256) {
            float val = smol[m];
            if (val != 0.f) {
                int a = atoms[molFirst + m];
                float inv = (a > 0) ? rsqrtf((float)a) : 0.f;
                atomicAdd(out + molFirst + m, val * inv);
            }
        }
    }
}

extern "C" void kernel_launch(void* const* d_in, const int* in_sizes, int n_in,
                              void* d_out, int out_size, void* d_ws, size_t ws_size,
                              hipStream_t stream) {
    const float* pos   = (const float*)d_in[0];
    const float* x     = (const float*)d_in[1];
    const float* eattr = (const float*)d_in[2];
    const float* W1_0  = (const float*)d_in[3];
    const float* W1_1  = (const float*)d_in[4];
    const float* W1_2  = (const float*)d_in[5];
    const float* W2_0  = (const float*)d_in[6];
    const float* W2_1  = (const float*)d_in[7];
    const float* W2_2  = (const float*)d_in[8];
    const int* esrc  = (const int*)d_in[9];
    const int* edst  = (const int*)d_in[10];
    const int* batch = (const int*)d_in[11];

    const int n_edges = in_sizes[9];       // 600000
    const int n_nodes = in_sizes[11];      // 50000
    const int n_mol   = out_size;          // 512
    float* out = (float*)d_out;

    const int BS = 256;
    const int NB = (n_nodes + BS - 1) / BS;              // 196
    const int EB4 = (n_edges / 4 + BS - 1) / BS;         // 4 edges/thread
    const int VB16 = (16 * n_nodes + BS - 1) / BS;       // 16 lanes/node
    const int GRID1 = (EB4 > NB) ? EB4 : NB;             // prep covers nodes+edges

    // Workspace layout; zeroed regions first.
    char* ws = (char*)d_ws;
    size_t off = 0;
    auto carve = [&](size_t bytes) {
        size_t o = off;
        off = (off + bytes + 255) & ~(size_t)255;
        return o;
    };
    size_t off_deg    = carve((size_t)n_nodes * sizeof(int));
    size_t off_atoms  = carve((size_t)n_mol * sizeof(int));
    size_t zero_bytes = off;
    size_t off_n1     = carve((size_t)n_nodes * sizeof(float4));
    size_t off_n2     = carve((size_t)n_nodes * sizeof(float2));
    size_t off_Pkg    = carve((size_t)n_nodes * 3 * sizeof(float4));
    size_t off_rec    = carve((size_t)n_nodes * MAXDEG * sizeof(int2));  // 19.2 MB
    (void)ws_size;

    int*    deg    = (int*)(ws + off_deg);
    int*    atoms  = (int*)(ws + off_atoms);
    float4* node1  = (float4*)(ws + off_n1);
    float2* node2  = (float2*)(ws + off_n2);
    float4* Pkg    = (float4*)(ws + off_Pkg);
    int2*   rec    = (int2*)(ws + off_rec);

    hipMemsetAsync(d_ws, 0, zero_bytes, stream);

    k_prep<<<GRID1, BS, 0, stream>>>(x, pos, W1_0, W1_1, W1_2, W2_0, W2_1, W2_2,
                                     esrc, edst, eattr, batch,
                                     node1, node2, deg, rec, atoms,
                                     n_nodes, n_edges);
    k_passA<<<VB16, BS, 0, stream>>>(node1, node2, rec, deg, Pkg, out, n_nodes, n_mol);
    k_passB<<<VB16, BS, 0, stream>>>(node1, Pkg, rec, deg, batch, atoms, out, n_nodes);
}

// Round 11
// 148.661 us; speedup vs baseline: 3.0807x; 1.0050x over previous
//
#include <hip/hip_runtime.h>

#define DEV_INLINE __device__ __forceinline__
#define MAXDEG 48  // deg ~ Poisson(12); P(deg>=48) ~ 5.6e-14 — guarded anyway

// sh[0..8]: l=0,1,2 real spherical harmonics as in reference _sh (first 9 comps)
static DEV_INLINE void sh_l012(float xx, float yy, float zz, float sh[9]) {
    const float s3  = 1.7320508075688772f;
    const float s5  = 2.23606797749979f;
    const float s15 = 3.872983346207417f;
    float r2 = xx * xx + yy * yy + zz * zz;
    sh[0] = 1.0f;
    sh[1] = s3 * xx;
    sh[2] = s3 * yy;
    sh[3] = s3 * zz;
    sh[4] = s15 * xx * yy;
    sh[5] = s15 * yy * zz;
    sh[6] = 0.5f * s5 * (3.0f * zz * zz - r2);
    sh[7] = s15 * xx * zz;
    sh[8] = 0.5f * s15 * (xx * xx - yy * yy);
}

// One staging pass (1 edge/thread for max atomic MLP):
//  nodes (first 196 blocks): node1[v]=(px,py,pz,b0), node2[v]=(b1,b2), atoms hist
//  edges (all 2344 blocks) : rank = deg[dst]++ (returning atomic), rec[dst*MAXDEG+rank]={src,ea}
__global__ void k_prep(const float* __restrict__ x,
                       const float* __restrict__ pos,
                       const float* __restrict__ W1_0, const float* __restrict__ W1_1,
                       const float* __restrict__ W1_2, const float* __restrict__ W2_0,
                       const float* __restrict__ W2_1, const float* __restrict__ W2_2,
                       const int* __restrict__ esrc, const int* __restrict__ edst,
                       const float* __restrict__ eattr, const int* __restrict__ batch,
                       float4* __restrict__ node1, float2* __restrict__ node2,
                       int* __restrict__ deg, int2* __restrict__ rec,
                       int* __restrict__ atoms,
                       int n_nodes, int n_edges) {
    __shared__ float ws[90];
    __shared__ int hist[512];
    int t = threadIdx.x;
    int g = blockIdx.x * blockDim.x + t;
    // issue edge loads early (independent of the node-phase work below)
    int dst = -1, src_v = 0;
    float ea = 0.f;
    if (g < n_edges) {
        dst = edst[g];
        src_v = esrc[g];
        ea = eattr[(size_t)g * 10];
    }
    bool nodeBlock = (blockIdx.x * blockDim.x) < n_nodes;  // uniform per block
    if (nodeBlock) {
        const float inv_s30 = 0.18257418583505536f;
        if (t < 30) {
            float s = 0.f;
            for (int u = 0; u < 64; u++) s += W1_0[t * 64 + u] * W2_0[u];
            ws[t] = s * inv_s30;
        } else if (t < 60) {
            int k = t - 30;
            float s = 0.f;
            for (int u = 0; u < 24; u++) s += W1_1[k * 24 + u] * W2_1[u];
            ws[t] = s * inv_s30;
        } else if (t < 90) {
            int k = t - 60;
            float s = 0.f;
            for (int u = 0; u < 16; u++) s += W1_2[k * 16 + u] * W2_2[u];
            ws[t] = s * inv_s30;
        }
        hist[t] = 0;
        hist[t + 256] = 0;
        __syncthreads();
        if (g < n_nodes) {
            const float* xv = x + (size_t)g * 30;
            float s0 = 0.f, s1 = 0.f, s2 = 0.f;
#pragma unroll
            for (int k = 0; k < 30; k++) {
                float xk = xv[k];
                s0 += xk * ws[k];
                s1 += xk * ws[30 + k];
                s2 += xk * ws[60 + k];
            }
            node1[g] = make_float4(pos[g * 3 + 0], pos[g * 3 + 1], pos[g * 3 + 2], s0);
            node2[g] = make_float2(s1, s2);
        }
        // atoms-per-mol histogram (batch sorted => small span per 256-node block)
        int v0 = blockIdx.x * 256;
        int molFirst = batch[min(v0, n_nodes - 1)];
        if (g < n_nodes) atomicAdd(&hist[batch[g] - molFirst], 1);
        __syncthreads();
        int vend = min(v0 + 255, n_nodes - 1);
        int molLast = batch[vend];
        for (int m = t; m <= molLast - molFirst; m += 256)
            if (hist[m] > 0) atomicAdd(atoms + molFirst + m, hist[m]);
    }
    if (dst >= 0) {
        int r = atomicAdd(deg + dst, 1);
        if (r < MAXDEG) rec[dst * MAXDEG + r] = make_int2(src_v, __float_as_int(ea));
    }
}

// Pass A: 16 lanes per dst node; row at rec + v*MAXDEG.
// Pkg[v] = { P0..P3, P4..P7, P8, px, py, pz } (3 float4; P scaled by isd).
// Also zeroes out[] (first n_mol threads) so passB can atomicAdd into it.
__global__ void k_passA(const float4* __restrict__ node1, const float2* __restrict__ node2,
                        const int2* __restrict__ rec, const int* __restrict__ deg,
                        float4* __restrict__ Pkg, float* __restrict__ out,
                        int n_nodes, int n_mol) {
    int g = blockIdx.x * blockDim.x + threadIdx.x;
    if (g < n_mol) out[g] = 0.f;
    int v = g >> 4, r = g & 15;
    if (v >= n_nodes) return;
    int d = min(deg[v], MAXDEG);
    const int2* row = rec + (size_t)v * MAXDEG;
    float4 pv = node1[v];
    float acc[9];
#pragma unroll
    for (int m = 0; m < 9; m++) acc[m] = 0.f;
    for (int i = r; i < d; i += 16) {
        int2 rcd = row[i];
        int src = rcd.x;
        float ea = __int_as_float(rcd.y);
        float4 n1 = node1[src];
        float2 n2 = node2[src];
        float dx = n1.x - pv.x, dy = n1.y - pv.y, dz = n1.z - pv.z;
        float sh[9];
        sh_l012(dx, dy, dz, sh);
        acc[0] += ea * n1.w;  // sh[0]==1, b0 in n1.w
#pragma unroll
        for (int m = 1; m < 4; m++) acc[m] += ea * sh[m] * n2.x;
#pragma unroll
        for (int m = 4; m < 9; m++) acc[m] += ea * sh[m] * n2.y;
    }
#pragma unroll
    for (int off = 1; off < 16; off <<= 1)
#pragma unroll
        for (int m = 0; m < 9; m++) acc[m] += __shfl_xor(acc[m], off);
    if (r == 0) {
        float s = (d > 0) ? rsqrtf((float)d) : 0.f;
        float4* o = Pkg + (size_t)v * 3;
        o[0] = make_float4(acc[0] * s, acc[1] * s, acc[2] * s, acc[3] * s);
        o[1] = make_float4(acc[4] * s, acc[5] * s, acc[6] * s, acc[7] * s);
        o[2] = make_float4(acc[8] * s, pv.x, pv.y, pv.z);
    }
}

// Pass B: 16 lanes per dst node; LDS mol aggregation; flush val*rsqrt(atoms) directly to out.
__global__ void k_passB(const float4* __restrict__ node1, const float4* __restrict__ Pkg,
                        const int2* __restrict__ rec, const int* __restrict__ deg,
                        const int* __restrict__ batch, const int* __restrict__ atoms,
                        float* __restrict__ out, int n_nodes) {
    __shared__ float smol[512];
    int t = threadIdx.x;
    smol[t] = 0.f;
    smol[t + 256] = 0.f;
    __syncthreads();
    int g = blockIdx.x * blockDim.x + t;
    int v = g >> 4, r = g & 15;
    int v0 = blockIdx.x * 16;                 // 16 nodes per block
    const float i3 = 0.5773502691896258f;     // 1/sqrt(3)
    const float i5 = 0.4472135954999579f;     // 1/sqrt(5)
    const float i104 = 0.09805806756909202f;  // 1/sqrt(104)
    int molFirst = batch[min(v0, n_nodes - 1)];
    if (v < n_nodes) {
        int d = min(deg[v], MAXDEG);
        const int2* row = rec + (size_t)v * MAXDEG;
        float4 pv = node1[v];
        float s = 0.f;
        for (int i = r; i < d; i += 16) {
            int2 rcd = row[i];
            int src = rcd.x;
            float ea = __int_as_float(rcd.y);
            const float4* Ps = Pkg + (size_t)src * 3;
            float4 p03 = Ps[0];
            float4 p47 = Ps[1];
            float4 p8p = Ps[2];
            float dx = p8p.y - pv.x, dy = p8p.z - pv.y, dz = p8p.w - pv.z;
            float sh[9];
            sh_l012(dx, dy, dz, sh);
            float t1 = sh[1] * p03.y + sh[2] * p03.z + sh[3] * p03.w;
            float t2 = sh[4] * p47.x + sh[5] * p47.y + sh[6] * p47.z + sh[7] * p47.w + sh[8] * p8p.x;
            s += ea * (p03.x + t1 * i3 + t2 * i5);
        }
#pragma unroll
        for (int off = 1; off < 16; off <<= 1) s += __shfl_xor(s, off);
        if (r == 0) {
            float isd = (d > 0) ? rsqrtf((float)d) : 0.f;
            atomicAdd(&smol[batch[v] - molFirst], s * i104 * isd);
        }
    }
    __syncthreads();
    if (v0 < n_nodes) {
        int vend = min(v0 + 15, n_nodes - 1);
        int nm = batch[vend] - molFirst + 1;
        for (int m = t; m < nm; m += 256) {
            float val = smol[m];
            if (val != 0.f) {
                int a = atoms[molFirst + m];
                float inv = (a > 0) ? rsqrtf((float)a) : 0.f;
                atomicAdd(out + molFirst + m, val * inv);
            }
        }
    }
}

extern "C" void kernel_launch(void* const* d_in, const int* in_sizes, int n_in,
                              void* d_out, int out_size, void* d_ws, size_t ws_size,
                              hipStream_t stream) {
    const float* pos   = (const float*)d_in[0];
    const float* x     = (const float*)d_in[1];
    const float* eattr = (const float*)d_in[2];
    const float* W1_0  = (const float*)d_in[3];
    const float* W1_1  = (const float*)d_in[4];
    const float* W1_2  = (const float*)d_in[5];
    const float* W2_0  = (const float*)d_in[6];
    const float* W2_1  = (const float*)d_in[7];
    const float* W2_2  = (const float*)d_in[8];
    const int* esrc  = (const int*)d_in[9];
    const int* edst  = (const int*)d_in[10];
    const int* batch = (const int*)d_in[11];

    const int n_edges = in_sizes[9];       // 600000
    const int n_nodes = in_sizes[11];      // 50000
    const int n_mol   = out_size;          // 512
    float* out = (float*)d_out;

    const int BS = 256;
    const int NB = (n_nodes + BS - 1) / BS;              // 196
    const int EB1 = (n_edges + BS - 1) / BS;             // 2344, 1 edge/thread
    const int VB16 = (16 * n_nodes + BS - 1) / BS;       // 16 lanes/node
    const int GRID1 = (EB1 > NB) ? EB1 : NB;             // prep covers nodes+edges

    // Workspace layout; zeroed regions first.
    char* ws = (char*)d_ws;
    size_t off = 0;
    auto carve = [&](size_t bytes) {
        size_t o = off;
        off = (off + bytes + 255) & ~(size_t)255;
        return o;
    };
    size_t off_deg    = carve((size_t)n_nodes * sizeof(int));
    size_t off_atoms  = carve((size_t)n_mol * sizeof(int));
    size_t zero_bytes = off;
    size_t off_n1     = carve((size_t)n_nodes * sizeof(float4));
    size_t off_n2     = carve((size_t)n_nodes * sizeof(float2));
    size_t off_Pkg    = carve((size_t)n_nodes * 3 * sizeof(float4));
    size_t off_rec    = carve((size_t)n_nodes * MAXDEG * sizeof(int2));  // 19.2 MB
    (void)ws_size;

    int*    deg    = (int*)(ws + off_deg);
    int*    atoms  = (int*)(ws + off_atoms);
    float4* node1  = (float4*)(ws + off_n1);
    float2* node2  = (float2*)(ws + off_n2);
    float4* Pkg    = (float4*)(ws + off_Pkg);
    int2*   rec    = (int2*)(ws + off_rec);

    hipMemsetAsync(d_ws, 0, zero_bytes, stream);

    k_prep<<<GRID1, BS, 0, stream>>>(x, pos, W1_0, W1_1, W1_2, W2_0, W2_1, W2_2,
                                     esrc, edst, eattr, batch,
                                     node1, node2, deg, rec, atoms,
                                     n_nodes, n_edges);
    k_passA<<<VB16, BS, 0, stream>>>(node1, node2, rec, deg, Pkg, out, n_nodes, n_mol);
    k_passB<<<VB16, BS, 0, stream>>>(node1, Pkg, rec, deg, batch, atoms, out, n_nodes);
}